// Round 1
// baseline (304.035 us; speedup 1.0000x reference)
//
#include <hip/hip_runtime.h>

// Problem: TextEncoder_1898375545588
// texts (64,514,768) f32; word_starts/ends (64,256) i32; word_length (64,) i32
// W1 (768,500) b1(500) W2 (500,300) b2(300) gamma/beta (300)
// out: (64,256,300) f32
// Pipeline: segment-mean pool -> relu(x@W1+b1) -> relu(h@W2+b2) -> LayerNorm

#define N_  64
#define L_  514
#define D_  768
#define W_  256
#define H1_ 500
#define H2_ 300
#define LN_EPS 1e-5f
#define M_  (N_ * W_)   // 16384 rows

// ---------------------------------------------------------------- pooling ---
// One block per (n,w). 192 threads x float4 = 768 dims. Segments are 1-2 rows.
__global__ __launch_bounds__(192) void pool_kernel(
    const float* __restrict__ texts, const int* __restrict__ wstart,
    const int* __restrict__ wend, const int* __restrict__ wlen,
    float* __restrict__ pooled)
{
    int idx = blockIdx.x;          // n*W + w
    int n = idx >> 8;
    int w = idx & (W_ - 1);
    int s = wstart[idx], e = wend[idx];
    bool live = (w < wlen[n]);
    int d = threadIdx.x * 4;
    float4 acc = make_float4(0.f, 0.f, 0.f, 0.f);
    if (live) {
        // tok row i == texts row i+1
        const float* base = texts + ((size_t)n * L_ + 1) * D_ + d;
        for (int i = s; i < e; ++i) {
            float4 v = *reinterpret_cast<const float4*>(base + (size_t)i * D_);
            acc.x += v.x; acc.y += v.y; acc.z += v.z; acc.w += v.w;
        }
        float inv = 1.0f / (float)max(e - s, 1);
        acc.x *= inv; acc.y *= inv; acc.z *= inv; acc.w *= inv;
    }
    *reinterpret_cast<float4*>(pooled + (size_t)idx * D_ + d) = acc;
}

// ------------------------------------------------------- fp32 tiled GEMM ---
// C[M x Nc] = relu(A[M x K] @ B[K x Nc] + bias[Nc]); all row-major.
// BM=64, BN=64, BK=16; 256 threads; 4x4 micro-tile per thread.
template<int BM, int BN, int BK>
__global__ __launch_bounds__(256) void gemm_bias_relu(
    const float* __restrict__ A, const float* __restrict__ B,
    const float* __restrict__ bias, float* __restrict__ C,
    int M, int K, int Nc)
{
    __shared__ float As[BK][BM + 1];  // +1 pad: transposed stores
    __shared__ float Bs[BK][BN];

    const int bm = blockIdx.y * BM;
    const int bn = blockIdx.x * BN;
    const int tid = threadIdx.x;
    const int tm = (tid / (BN / 4)) * 4;   // 0..60
    const int tn = (tid % (BN / 4)) * 4;   // 0..60

    float acc[4][4] = {};

    for (int k0 = 0; k0 < K; k0 += BK) {
        // A tile: BM x BK (rows always in-range: M % BM == 0)
        {
            int r = tid / (BK / 4);          // 0..63
            int c = (tid % (BK / 4)) * 4;    // 0,4,8,12
            int gk = k0 + c;
            const float* ap = A + (size_t)(bm + r) * K + gk;
            float4 v;
            if (gk + 3 < K) {
                v = *reinterpret_cast<const float4*>(ap);
            } else {
                v.x = (gk + 0 < K) ? ap[0] : 0.f;
                v.y = (gk + 1 < K) ? ap[1] : 0.f;
                v.z = (gk + 2 < K) ? ap[2] : 0.f;
                v.w = (gk + 3 < K) ? ap[3] : 0.f;
            }
            As[c + 0][r] = v.x; As[c + 1][r] = v.y;
            As[c + 2][r] = v.z; As[c + 3][r] = v.w;
        }
        // B tile: BK x BN
        {
            int r = tid / (BN / 4);          // 0..15
            int c = (tid % (BN / 4)) * 4;    // 0..60
            int gk = k0 + r;
            int gc = bn + c;
            float4 v = make_float4(0.f, 0.f, 0.f, 0.f);
            if (gk < K) {
                const float* bp = B + (size_t)gk * Nc + gc;
                if (gc + 3 < Nc) {
                    v = *reinterpret_cast<const float4*>(bp);
                } else {
                    if (gc + 0 < Nc) v.x = bp[0];
                    if (gc + 1 < Nc) v.y = bp[1];
                    if (gc + 2 < Nc) v.z = bp[2];
                    if (gc + 3 < Nc) v.w = bp[3];
                }
            }
            Bs[r][c + 0] = v.x; Bs[r][c + 1] = v.y;
            Bs[r][c + 2] = v.z; Bs[r][c + 3] = v.w;
        }
        __syncthreads();

        #pragma unroll
        for (int kk = 0; kk < BK; ++kk) {
            float a0 = As[kk][tm + 0], a1 = As[kk][tm + 1],
                  a2 = As[kk][tm + 2], a3 = As[kk][tm + 3];
            float b0 = Bs[kk][tn + 0], b1v = Bs[kk][tn + 1],
                  b2v = Bs[kk][tn + 2], b3 = Bs[kk][tn + 3];
            acc[0][0] += a0 * b0;  acc[0][1] += a0 * b1v;
            acc[0][2] += a0 * b2v; acc[0][3] += a0 * b3;
            acc[1][0] += a1 * b0;  acc[1][1] += a1 * b1v;
            acc[1][2] += a1 * b2v; acc[1][3] += a1 * b3;
            acc[2][0] += a2 * b0;  acc[2][1] += a2 * b1v;
            acc[2][2] += a2 * b2v; acc[2][3] += a2 * b3;
            acc[3][0] += a3 * b0;  acc[3][1] += a3 * b1v;
            acc[3][2] += a3 * b2v; acc[3][3] += a3 * b3;
        }
        __syncthreads();
    }

    #pragma unroll
    for (int i = 0; i < 4; ++i) {
        int row = bm + tm + i;
        #pragma unroll
        for (int j = 0; j < 4; ++j) {
            int col = bn + tn + j;
            if (col < Nc) {
                float v = acc[i][j] + bias[col];
                C[(size_t)row * Nc + col] = v > 0.f ? v : 0.f;
            }
        }
    }
}

// ------------------------------------------------------------- layernorm ---
// One 256-thread block per row of 300; in-place on d_out.
__global__ __launch_bounds__(256) void ln_kernel(
    float* __restrict__ h, const float* __restrict__ gamma,
    const float* __restrict__ beta)
{
    float* p = h + (size_t)blockIdx.x * H2_;
    int tid = threadIdx.x;

    float v0 = (tid < H2_) ? p[tid] : 0.f;
    float v1 = (tid + 256 < H2_) ? p[tid + 256] : 0.f;
    float s = v0 + v1;
    float sq = v0 * v0 + v1 * v1;

    #pragma unroll
    for (int off = 32; off > 0; off >>= 1) {
        s  += __shfl_down(s, off);
        sq += __shfl_down(sq, off);
    }
    __shared__ float s_sum[4], s_sq[4];
    int wid = tid >> 6, lane = tid & 63;
    if (lane == 0) { s_sum[wid] = s; s_sq[wid] = sq; }
    __syncthreads();
    float S  = s_sum[0] + s_sum[1] + s_sum[2] + s_sum[3];
    float SQ = s_sq[0] + s_sq[1] + s_sq[2] + s_sq[3];
    float mu = S * (1.0f / H2_);
    float var = SQ * (1.0f / H2_) - mu * mu;
    float rstd = rsqrtf(var + LN_EPS);

    if (tid < H2_)       p[tid]       = (v0 - mu) * rstd * gamma[tid]       + beta[tid];
    if (tid + 256 < H2_) p[tid + 256] = (v1 - mu) * rstd * gamma[tid + 256] + beta[tid + 256];
}

// ----------------------------------------------------------------- launch ---
extern "C" void kernel_launch(void* const* d_in, const int* in_sizes, int n_in,
                              void* d_out, int out_size, void* d_ws, size_t ws_size,
                              hipStream_t stream)
{
    const float* texts  = (const float*)d_in[0];
    const int*   wstart = (const int*)  d_in[1];
    const int*   wend   = (const int*)  d_in[2];
    const int*   wlen   = (const int*)  d_in[3];
    const float* W1     = (const float*)d_in[4];
    const float* b1     = (const float*)d_in[5];
    const float* W2     = (const float*)d_in[6];
    const float* b2     = (const float*)d_in[7];
    const float* gamma  = (const float*)d_in[8];
    const float* beta   = (const float*)d_in[9];
    float* out = (float*)d_out;

    // workspace: pooled (M_ x D_) = 50.3 MB, h1 (M_ x H1_) = 32.8 MB
    char* ws = (char*)d_ws;
    float* pooled = (float*)ws;
    float* h1     = (float*)(ws + (size_t)M_ * D_ * sizeof(float));

    pool_kernel<<<M_, 192, 0, stream>>>(texts, wstart, wend, wlen, pooled);

    dim3 g1((H1_ + 63) / 64, M_ / 64);   // 8 x 256
    gemm_bias_relu<64, 64, 16><<<g1, 256, 0, stream>>>(pooled, W1, b1, h1, M_, D_, H1_);

    dim3 g2((H2_ + 63) / 64, M_ / 64);   // 5 x 256
    gemm_bias_relu<64, 64, 16><<<g2, 256, 0, stream>>>(h1, W2, b2, out, M_, H1_, H2_);

    ln_kernel<<<M_, 256, 0, stream>>>(out, gamma, beta);
}

// Round 2
// 97.509 us; speedup vs baseline: 3.1180x; 3.1180x over previous
//
#include <hip/hip_runtime.h>
#include <hip/hip_bf16.h>

// TextEncoder: segment-mean pool -> relu(x@W1+b1) -> relu(h@W2+b2) -> LayerNorm
// bf16 MFMA path: pooled/h1/weights in bf16, fp32 accum, fp32 LN.
//
// Padding scheme (ragged N): W1T = [512][768] (rows >=500 zero), b1 guarded ->
// h1 pad cols = relu(0)=0; W2T = [320][512] (k>=500 rows zero, n>=300 zero).
// So both GEMMs have clean BM/BN/BK-divisible shapes, no K guards.

#define N_  64
#define L_  514
#define D_  768
#define W_  256
#define H1_ 500
#define H1P 512
#define H2_ 300
#define H2P 320
#define LN_EPS 1e-5f
#define M_  (N_ * W_)   // 16384 rows

typedef __bf16 bf16x8 __attribute__((ext_vector_type(8)));
typedef float  f32x4  __attribute__((ext_vector_type(4)));

__device__ __forceinline__ void load_lds16(const void* g, void* l) {
    __builtin_amdgcn_global_load_lds(
        (const __attribute__((address_space(1))) void*)g,
        (__attribute__((address_space(3))) void*)l, 16, 0, 0);
}

// ---------------------------------------------------------------- pooling ---
// One block per (n,w); 192 threads x 4 dims = 768. Output bf16.
__global__ __launch_bounds__(192) void pool_kernel(
    const float* __restrict__ texts, const int* __restrict__ wstart,
    const int* __restrict__ wend, const int* __restrict__ wlen,
    __hip_bfloat16* __restrict__ pooled)
{
    int idx = blockIdx.x;          // n*W + w
    int n = idx >> 8;
    int w = idx & (W_ - 1);
    int s = wstart[idx], e = wend[idx];
    bool live = (w < wlen[n]);
    int d = threadIdx.x * 4;
    float4 acc = make_float4(0.f, 0.f, 0.f, 0.f);
    if (live) {
        const float* base = texts + ((size_t)n * L_ + 1) * D_ + d;  // tok = texts[:,1:-1]
        for (int i = s; i < e; ++i) {
            float4 v = *reinterpret_cast<const float4*>(base + (size_t)i * D_);
            acc.x += v.x; acc.y += v.y; acc.z += v.z; acc.w += v.w;
        }
        float inv = 1.0f / (float)max(e - s, 1);
        acc.x *= inv; acc.y *= inv; acc.z *= inv; acc.w *= inv;
    }
    union { __hip_bfloat16 h[4]; uint2 u; } o;
    o.h[0] = __float2bfloat16(acc.x); o.h[1] = __float2bfloat16(acc.y);
    o.h[2] = __float2bfloat16(acc.z); o.h[3] = __float2bfloat16(acc.w);
    *reinterpret_cast<uint2*>(pooled + (size_t)idx * D_ + d) = o.u;
}

// -------------------------------------------------- weight convert+transpose
// W1T[n][k] (bf16, [H1P][D_]) = W1[k][n]; zero pad n>=H1_.
__global__ __launch_bounds__(256) void convW1_kernel(
    const float* __restrict__ W1, __hip_bfloat16* __restrict__ W1T)
{
    int t = blockIdx.x * 256 + threadIdx.x;     // over H1P*D_
    int n = t / D_, k = t - n * D_;
    float v = (n < H1_) ? W1[(size_t)k * H1_ + n] : 0.f;
    W1T[t] = __float2bfloat16(v);
}

// W2T[n][k] (bf16, [H2P][H1P]) = W2[k][n]; zero pad n>=H2_, k>=H1_.
__global__ __launch_bounds__(256) void convW2_kernel(
    const float* __restrict__ W2, __hip_bfloat16* __restrict__ W2T)
{
    int t = blockIdx.x * 256 + threadIdx.x;     // over H2P*H1P
    int n = t / H1P, k = t - n * H1P;
    float v = (n < H2_ && k < H1_) ? W2[(size_t)k * H2_ + n] : 0.f;
    W2T[t] = __float2bfloat16(v);
}

// ------------------------------------------------------------ MFMA GEMM ----
// C[M x N] = relu(A[M x K] @ B^T[N x K] + bias); A,B bf16 row-major (B stored
// N-major), C bf16 (MODE 0, ld=ldc) or f32 guarded col<biasN (MODE 1).
// 256 thr = 4 waves (2x2); wave tile (FM*16) x (FN*16); 16x16x32 bf16 MFMA.
// LDS: linear [rows][32] bf16 tiles; XOR swizzle ((row>>1)&3) on the 16B slot,
// applied on the global SOURCE of global_load_lds and on the ds_read address.
template<int BM, int BN, int FM, int FN, int MODE>
__global__ __launch_bounds__(256, 2) void gemm_mfma(
    const ushort* __restrict__ A, int lda,
    const ushort* __restrict__ B, int ldb,
    const float* __restrict__ bias, int biasN,
    void* __restrict__ outp, int ldc, int K)
{
    __shared__ __align__(16) char lds[(BM + BN) * 64];
    const int tid  = threadIdx.x;
    const int wave = tid >> 6, lane = tid & 63;
    const int wm = wave >> 1, wn = wave & 1;
    const int bm = blockIdx.y * BM, bn = blockIdx.x * BN;

    f32x4 acc[FM][FN] = {};
    const int ACH = BM / 16, TCH = (BM + BN) / 16;
    const int lrow = lane >> 2, lslot = lane & 3;
    const int g = lane >> 4, fr = lane & 15;

    for (int kt = 0; kt < K; kt += 32) {
        // stage: each wave handles chunks of 16 rows x 64B (1024B, lane*16 dest)
        for (int c = wave; c < TCH; c += 4) {
            int row, ldsoff, ld; const ushort* src;
            if (c < ACH) { row = c * 16 + lrow; src = A + (size_t)(bm + row) * lda; ldsoff = c * 1024; }
            else { int cc = c - ACH; row = cc * 16 + lrow;
                   src = B + (size_t)(bn + row) * ldb; ldsoff = BM * 64 + cc * 1024; }
            int sslot = lslot ^ ((row >> 1) & 3);
            load_lds16(src + kt + sslot * 8, lds + ldsoff);
        }
        __syncthreads();   // drains vmcnt -> tiles visible

        bf16x8 af[FM], bfr[FN];
        #pragma unroll
        for (int mi = 0; mi < FM; ++mi) {
            int r = wm * (FM * 16) + mi * 16 + fr;
            af[mi] = *(const bf16x8*)(lds + r * 64 + ((g ^ ((r >> 1) & 3)) << 4));
        }
        #pragma unroll
        for (int ni = 0; ni < FN; ++ni) {
            int r = wn * (FN * 16) + ni * 16 + fr;
            bfr[ni] = *(const bf16x8*)(lds + BM * 64 + r * 64 + ((g ^ ((r >> 1) & 3)) << 4));
        }
        #pragma unroll
        for (int mi = 0; mi < FM; ++mi)
            #pragma unroll
            for (int ni = 0; ni < FN; ++ni)
                acc[mi][ni] = __builtin_amdgcn_mfma_f32_16x16x32_bf16(
                    af[mi], bfr[ni], acc[mi][ni], 0, 0, 0);
        __syncthreads();
    }

    // epilogue: C/D layout col=lane&15, row=(lane>>4)*4+reg  [m89-verified]
    #pragma unroll
    for (int mi = 0; mi < FM; ++mi) {
        #pragma unroll
        for (int ni = 0; ni < FN; ++ni) {
            int col = bn + wn * (FN * 16) + ni * 16 + fr;
            float bv = (col < biasN) ? bias[col] : 0.f;
            #pragma unroll
            for (int j = 0; j < 4; ++j) {
                int row = bm + wm * (FM * 16) + mi * 16 + g * 4 + j;
                float v = acc[mi][ni][j] + bv;
                v = v > 0.f ? v : 0.f;
                if (MODE == 0) {
                    ((__hip_bfloat16*)outp)[(size_t)row * ldc + col] = __float2bfloat16(v);
                } else {
                    if (col < biasN) ((float*)outp)[(size_t)row * ldc + col] = v;
                }
            }
        }
    }
}

// ------------------------------------------------------------- layernorm ---
__global__ __launch_bounds__(256) void ln_kernel(
    float* __restrict__ h, const float* __restrict__ gamma,
    const float* __restrict__ beta)
{
    float* p = h + (size_t)blockIdx.x * H2_;
    int tid = threadIdx.x;

    float v0 = p[tid % H2_];                       // tid<256 always < 300
    v0 = (tid < H2_) ? p[tid] : 0.f;
    float v1 = (tid + 256 < H2_) ? p[tid + 256] : 0.f;
    float s = v0 + v1;
    float sq = v0 * v0 + v1 * v1;

    #pragma unroll
    for (int off = 32; off > 0; off >>= 1) {
        s  += __shfl_down(s, off);
        sq += __shfl_down(sq, off);
    }
    __shared__ float s_sum[4], s_sq[4];
    int wid = tid >> 6, lane = tid & 63;
    if (lane == 0) { s_sum[wid] = s; s_sq[wid] = sq; }
    __syncthreads();
    float S  = s_sum[0] + s_sum[1] + s_sum[2] + s_sum[3];
    float SQ = s_sq[0] + s_sq[1] + s_sq[2] + s_sq[3];
    float mu = S * (1.0f / H2_);
    float var = SQ * (1.0f / H2_) - mu * mu;
    float rstd = rsqrtf(var + LN_EPS);

    if (tid < H2_)       p[tid]       = (v0 - mu) * rstd * gamma[tid]       + beta[tid];
    if (tid + 256 < H2_) p[tid + 256] = (v1 - mu) * rstd * gamma[tid + 256] + beta[tid + 256];
}

// ----------------------------------------------------------------- launch ---
extern "C" void kernel_launch(void* const* d_in, const int* in_sizes, int n_in,
                              void* d_out, int out_size, void* d_ws, size_t ws_size,
                              hipStream_t stream)
{
    const float* texts  = (const float*)d_in[0];
    const int*   wstart = (const int*)  d_in[1];
    const int*   wend   = (const int*)  d_in[2];
    const int*   wlen   = (const int*)  d_in[3];
    const float* W1     = (const float*)d_in[4];
    const float* b1     = (const float*)d_in[5];
    const float* W2     = (const float*)d_in[6];
    const float* b2     = (const float*)d_in[7];
    const float* gamma  = (const float*)d_in[8];
    const float* beta   = (const float*)d_in[9];
    float* out = (float*)d_out;

    // workspace (bf16): pooled M x 768 (25.2MB), h1 M x 512 (16.8MB),
    // W1T 512x768 (0.79MB), W2T 320x512 (0.33MB)
    ushort* pooled = (ushort*)d_ws;
    ushort* h1     = pooled + (size_t)M_ * D_;
    ushort* W1T    = h1 + (size_t)M_ * H1P;
    ushort* W2T    = W1T + (size_t)H1P * D_;

    convW1_kernel<<<(H1P * D_) / 256, 256, 0, stream>>>(W1, (__hip_bfloat16*)W1T);
    convW2_kernel<<<(H2P * H1P) / 256, 256, 0, stream>>>(W2, (__hip_bfloat16*)W2T);
    pool_kernel<<<M_, 192, 0, stream>>>(texts, wstart, wend, wlen, (__hip_bfloat16*)pooled);

    // GEMM1: (M x 768) @ (768 x 512pad) -> h1 bf16 [M][512]
    dim3 g1(H1P / 128, M_ / 128);   // 4 x 128
    gemm_mfma<128, 128, 4, 4, 0><<<g1, 256, 0, stream>>>(
        pooled, D_, W1T, D_, b1, H1_, h1, H1P, D_);

    // GEMM2: (M x 512) @ (512 x 320pad) -> out f32 [M][300]
    dim3 g2(H2P / 64, M_ / 128);    // 5 x 128
    gemm_mfma<128, 64, 4, 2, 1><<<g2, 256, 0, stream>>>(
        h1, H1P, W2T, H1P, b2, H2_, out, H2_, H1P);

    ln_kernel<<<M_, 256, 0, stream>>>(out, gamma, beta);
}

// Round 3
// 72.348 us; speedup vs baseline: 4.2024x; 1.3478x over previous
//
#include <hip/hip_runtime.h>
#include <hip/hip_bf16.h>

// TextEncoder: segment-mean pool -> relu(x@W1+b1) -> relu(h@W2+b2) -> LayerNorm
// bf16 MFMA path, fp32 accum/LN. R3: 2-phase pipelined GEMMs (T3 minimum),
// LN fused into GEMM2 epilogue, prep kernels merged into one launch.
//
// Padding: W1T=[512][768] (rows>=500 zero) so h1 pad cols = relu(0)=0;
// W2T=[320][512] (k>=500, n>=300 zero) -> pad output cols are exactly 0 and
// contribute nothing to the LN sums (divide by 300, skip writes >=300).

#define N_  64
#define L_  514
#define D_  768
#define W_  256
#define H1_ 500
#define H1P 512
#define H2_ 300
#define H2P 320
#define LN_EPS 1e-5f
#define M_  (N_ * W_)   // 16384

typedef __bf16 bf16x8 __attribute__((ext_vector_type(8)));
typedef float  f32x4  __attribute__((ext_vector_type(4)));

__device__ __forceinline__ void load_lds16(const void* g, void* l) {
    __builtin_amdgcn_global_load_lds(
        (const __attribute__((address_space(1))) void*)g,
        (__attribute__((address_space(3))) void*)l, 16, 0, 0);
}

// ------------------------------------------------------------------ prep ---
// blocks [0, M_): pooling, one block per (n,w), 192 thr x float4 = 768 dims.
// blocks [M_, M_+CONV1_B): W1 -> W1T bf16 transpose+pad
// blocks [M_+CONV1_B, ...): W2 -> W2T bf16 transpose+pad
#define CONV1_ELEMS (H1P * D_)     // 393216
#define CONV2_ELEMS (H2P * H1P)    // 163840
#define CONV1_B ((CONV1_ELEMS + 191) / 192)   // 2048
#define CONV2_B ((CONV2_ELEMS + 191) / 192)   // 854

__global__ __launch_bounds__(192) void prep_kernel(
    const float* __restrict__ texts, const int* __restrict__ wstart,
    const int* __restrict__ wend, const int* __restrict__ wlen,
    const float* __restrict__ W1, const float* __restrict__ W2,
    __hip_bfloat16* __restrict__ pooled, __hip_bfloat16* __restrict__ W1T,
    __hip_bfloat16* __restrict__ W2T)
{
    int b = blockIdx.x;
    if (b < M_) {
        int n = b >> 8;
        int w = b & (W_ - 1);
        int s = wstart[b], e = wend[b];
        bool live = (w < wlen[n]);
        int d = threadIdx.x * 4;
        float4 acc = make_float4(0.f, 0.f, 0.f, 0.f);
        if (live) {
            const float* base = texts + ((size_t)n * L_ + 1) * D_ + d;  // tok=texts[:,1:-1]
            for (int i = s; i < e; ++i) {
                float4 v = *reinterpret_cast<const float4*>(base + (size_t)i * D_);
                acc.x += v.x; acc.y += v.y; acc.z += v.z; acc.w += v.w;
            }
            float inv = 1.0f / (float)max(e - s, 1);
            acc.x *= inv; acc.y *= inv; acc.z *= inv; acc.w *= inv;
        }
        union { __hip_bfloat16 h[4]; uint2 u; } o;
        o.h[0] = __float2bfloat16(acc.x); o.h[1] = __float2bfloat16(acc.y);
        o.h[2] = __float2bfloat16(acc.z); o.h[3] = __float2bfloat16(acc.w);
        *reinterpret_cast<uint2*>(pooled + (size_t)b * D_ + d) = o.u;
    } else if (b < M_ + CONV1_B) {
        int t = (b - M_) * 192 + threadIdx.x;
        if (t < CONV1_ELEMS) {
            int n = t / D_, k = t - n * D_;
            float v = (n < H1_) ? W1[(size_t)k * H1_ + n] : 0.f;
            W1T[t] = __float2bfloat16(v);
        }
    } else {
        int t = (b - M_ - CONV1_B) * 192 + threadIdx.x;
        if (t < CONV2_ELEMS) {
            int n = t >> 9, k = t & (H1P - 1);
            float v = (n < H2_ && k < H1_) ? W2[(size_t)k * H2_ + n] : 0.f;
            W2T[t] = __float2bfloat16(v);
        }
    }
}

// --------------------------------------------------------- GEMM1 (MFMA) ----
// C[M x N] = relu(A @ B^T + bias) in bf16. 2-phase double-buffered.
// 256 thr = 4 waves (2x2); BM=BN=128; FM=FN=4; 16x16x32 bf16 MFMA.
// LDS tiles [rows][32 bf16]; XOR swizzle ((row>>1)&3) on the 16B slot applied
// to the global SOURCE (linear LDS dest, rule #21) and on the ds_read addr.
template<int BM, int BN, int FM, int FN>
__global__ __launch_bounds__(256, 2) void gemm_mfma(
    const ushort* __restrict__ A, int lda,
    const ushort* __restrict__ B, int ldb,
    const float* __restrict__ bias, int biasN,
    __hip_bfloat16* __restrict__ outp, int ldc, int K)
{
    constexpr int BUFB = (BM + BN) * 64;
    __shared__ __align__(16) char lds[2 * BUFB];
    const int tid  = threadIdx.x;
    const int wave = tid >> 6, lane = tid & 63;
    const int wm = wave >> 1, wn = wave & 1;
    const int bm = blockIdx.y * BM, bn = blockIdx.x * BN;
    const int ACH = BM / 16, TCH = (BM + BN) / 16;
    const int lrow = lane >> 2, lslot = lane & 3;
    const int g = lane >> 4, fr = lane & 15;

    f32x4 acc[FM][FN] = {};

    auto stage = [&](int buf, int kt) {
        char* base = lds + buf * BUFB;
        for (int c = wave; c < TCH; c += 4) {
            int row, ldsoff; const ushort* src;
            if (c < ACH) { row = c * 16 + lrow;
                           src = A + (size_t)(bm + row) * lda; ldsoff = c * 1024; }
            else { int cc = c - ACH; row = cc * 16 + lrow;
                   src = B + (size_t)(bn + row) * ldb; ldsoff = BM * 64 + cc * 1024; }
            int sslot = lslot ^ ((row >> 1) & 3);
            load_lds16(src + kt + sslot * 8, base + ldsoff);
        }
    };

    stage(0, 0);
    __syncthreads();
    int cur = 0;
    const int NT = K / 32;
    for (int t = 0; t < NT; ++t) {
        if (t + 1 < NT) stage(cur ^ 1, (t + 1) * 32);   // overlaps with compute below
        const char* base = lds + cur * BUFB;
        bf16x8 af[FM], bfr[FN];
        #pragma unroll
        for (int mi = 0; mi < FM; ++mi) {
            int r = wm * (FM * 16) + mi * 16 + fr;
            af[mi] = *(const bf16x8*)(base + r * 64 + ((g ^ ((r >> 1) & 3)) << 4));
        }
        #pragma unroll
        for (int ni = 0; ni < FN; ++ni) {
            int r = wn * (FN * 16) + ni * 16 + fr;
            bfr[ni] = *(const bf16x8*)(base + BM * 64 + r * 64 + ((g ^ ((r >> 1) & 3)) << 4));
        }
        #pragma unroll
        for (int mi = 0; mi < FM; ++mi)
            #pragma unroll
            for (int ni = 0; ni < FN; ++ni)
                acc[mi][ni] = __builtin_amdgcn_mfma_f32_16x16x32_bf16(
                    af[mi], bfr[ni], acc[mi][ni], 0, 0, 0);
        __syncthreads();   // drains next-tile vmcnt + barrier (one per K-step)
        cur ^= 1;
    }

    // epilogue: C/D layout col=lane&15, row=(lane>>4)*4+j
    #pragma unroll
    for (int mi = 0; mi < FM; ++mi) {
        #pragma unroll
        for (int ni = 0; ni < FN; ++ni) {
            int col = bn + wn * (FN * 16) + ni * 16 + fr;
            float bv = (col < biasN) ? bias[col] : 0.f;
            #pragma unroll
            for (int j = 0; j < 4; ++j) {
                int row = bm + wm * (FM * 16) + mi * 16 + g * 4 + j;
                float v = acc[mi][ni][j] + bv;
                outp[(size_t)row * ldc + col] = __float2bfloat16(v > 0.f ? v : 0.f);
            }
        }
    }
}

// ------------------------------------------- GEMM2 + bias + relu + LN ------
// out[M x 300] = LN(relu(h1 @ W2T^T + b2)). One block owns 64 full rows:
// BM=64, BN=320 (full padded N), K=512. 512 thr = 8 waves (2 M x 4 N),
// wave tile 32 x 80 (FM=2, FN=5). Pad cols are exactly 0 -> sums over 320
// equal sums over 300. Grid = 256 blocks (1/CU).
__global__ __launch_bounds__(512, 1) void gemm2_ln_kernel(
    const ushort* __restrict__ A, const ushort* __restrict__ B,
    const float* __restrict__ bias, const float* __restrict__ gamma,
    const float* __restrict__ beta, float* __restrict__ out)
{
    constexpr int BM = 64, BN = 320, FM = 2, FN = 5;
    constexpr int BUFB = (BM + BN) * 64;        // 24576
    __shared__ __align__(16) char lds[2 * BUFB];
    __shared__ float red[2][32][4][2];          // [wm][row][wn][sum|sq]
    const int tid  = threadIdx.x;
    const int wave = tid >> 6, lane = tid & 63;
    const int wm = wave >> 2, wn = wave & 3;    // 2 x 4
    const int bm = blockIdx.x * BM;
    const int ACH = BM / 16 /*4*/, TCH = (BM + BN) / 16 /*24*/;
    const int lrow = lane >> 2, lslot = lane & 3;
    const int g = lane >> 4, fr = lane & 15;

    f32x4 acc[FM][FN] = {};

    auto stage = [&](int buf, int kt) {
        char* base = lds + buf * BUFB;
        #pragma unroll
        for (int c0 = 0; c0 < 3; ++c0) {        // 24 chunks / 8 waves
            int c = wave + c0 * 8;
            int row, ldsoff; const ushort* src;
            if (c < ACH) { row = c * 16 + lrow;
                           src = A + (size_t)(bm + row) * H1P; ldsoff = c * 1024; }
            else { int cc = c - ACH; row = cc * 16 + lrow;
                   src = B + (size_t)row * H1P; ldsoff = BM * 64 + cc * 1024; }
            int sslot = lslot ^ ((row >> 1) & 3);
            load_lds16(src + kt + sslot * 8, base + ldsoff);
        }
    };

    stage(0, 0);
    __syncthreads();
    int cur = 0;
    constexpr int NT = H1P / 32;   // 16
    for (int t = 0; t < NT; ++t) {
        if (t + 1 < NT) stage(cur ^ 1, (t + 1) * 32);
        const char* base = lds + cur * BUFB;
        bf16x8 af[FM], bfr[FN];
        #pragma unroll
        for (int mi = 0; mi < FM; ++mi) {
            int r = wm * 32 + mi * 16 + fr;
            af[mi] = *(const bf16x8*)(base + r * 64 + ((g ^ ((r >> 1) & 3)) << 4));
        }
        #pragma unroll
        for (int ni = 0; ni < FN; ++ni) {
            int r = wn * 80 + ni * 16 + fr;
            bfr[ni] = *(const bf16x8*)(base + BM * 64 + r * 64 + ((g ^ ((r >> 1) & 3)) << 4));
        }
        #pragma unroll
        for (int mi = 0; mi < FM; ++mi)
            #pragma unroll
            for (int ni = 0; ni < FN; ++ni)
                acc[mi][ni] = __builtin_amdgcn_mfma_f32_16x16x32_bf16(
                    af[mi], bfr[ni], acc[mi][ni], 0, 0, 0);
        __syncthreads();
        cur ^= 1;
    }

    // ---- epilogue: bias+relu in regs, per-row mean/var, normalize, write ----
    float vals[FM][FN][4];
    float rsum[FM][4] = {}, rsq[FM][4] = {};
    #pragma unroll
    for (int ni = 0; ni < FN; ++ni) {
        int col = wn * 80 + ni * 16 + fr;
        float bv = (col < H2_) ? bias[col] : 0.f;
        #pragma unroll
        for (int mi = 0; mi < FM; ++mi)
            #pragma unroll
            for (int j = 0; j < 4; ++j) {
                float v = acc[mi][ni][j] + bv;
                v = v > 0.f ? v : 0.f;
                vals[mi][ni][j] = v;
                rsum[mi][j] += v;
                rsq[mi][j]  += v * v;
            }
    }
    // reduce across the 16-lane fr group (cols of this wave)
    #pragma unroll
    for (int off = 1; off < 16; off <<= 1)
        #pragma unroll
        for (int mi = 0; mi < FM; ++mi)
            #pragma unroll
            for (int j = 0; j < 4; ++j) {
                rsum[mi][j] += __shfl_xor(rsum[mi][j], off);
                rsq[mi][j]  += __shfl_xor(rsq[mi][j], off);
            }
    if (fr == 0) {
        #pragma unroll
        for (int mi = 0; mi < FM; ++mi)
            #pragma unroll
            for (int j = 0; j < 4; ++j) {
                int r32 = mi * 16 + g * 4 + j;
                red[wm][r32][wn][0] = rsum[mi][j];
                red[wm][r32][wn][1] = rsq[mi][j];
            }
    }
    __syncthreads();
    #pragma unroll
    for (int mi = 0; mi < FM; ++mi) {
        #pragma unroll
        for (int j = 0; j < 4; ++j) {
            int r32 = mi * 16 + g * 4 + j;
            float S  = red[wm][r32][0][0] + red[wm][r32][1][0]
                     + red[wm][r32][2][0] + red[wm][r32][3][0];
            float SQ = red[wm][r32][0][1] + red[wm][r32][1][1]
                     + red[wm][r32][2][1] + red[wm][r32][3][1];
            float mu   = S * (1.0f / H2_);
            float var  = SQ * (1.0f / H2_) - mu * mu;
            float rstd = rsqrtf(var + LN_EPS);
            int row = bm + wm * 32 + r32;
            #pragma unroll
            for (int ni = 0; ni < FN; ++ni) {
                int col = wn * 80 + ni * 16 + fr;
                if (col < H2_)
                    out[(size_t)row * H2_ + col] =
                        (vals[mi][ni][j] - mu) * rstd * gamma[col] + beta[col];
            }
        }
    }
}

// ----------------------------------------------------------------- launch ---
extern "C" void kernel_launch(void* const* d_in, const int* in_sizes, int n_in,
                              void* d_out, int out_size, void* d_ws, size_t ws_size,
                              hipStream_t stream)
{
    const float* texts  = (const float*)d_in[0];
    const int*   wstart = (const int*)  d_in[1];
    const int*   wend   = (const int*)  d_in[2];
    const int*   wlen   = (const int*)  d_in[3];
    const float* W1     = (const float*)d_in[4];
    const float* b1     = (const float*)d_in[5];
    const float* W2     = (const float*)d_in[6];
    const float* b2     = (const float*)d_in[7];
    const float* gamma  = (const float*)d_in[8];
    const float* beta   = (const float*)d_in[9];
    float* out = (float*)d_out;

    ushort* pooled = (ushort*)d_ws;                 // M x 768 bf16
    ushort* h1     = pooled + (size_t)M_ * D_;      // M x 512 bf16
    ushort* W1T    = h1 + (size_t)M_ * H1P;         // 512 x 768 bf16
    ushort* W2T    = W1T + (size_t)H1P * D_;        // 320 x 512 bf16

    prep_kernel<<<M_ + CONV1_B + CONV2_B, 192, 0, stream>>>(
        texts, wstart, wend, wlen, W1, W2,
        (__hip_bfloat16*)pooled, (__hip_bfloat16*)W1T, (__hip_bfloat16*)W2T);

    dim3 g1(H1P / 128, M_ / 128);   // 4 x 128 = 512 blocks
    gemm_mfma<128, 128, 4, 4><<<g1, 256, 0, stream>>>(
        pooled, D_, W1T, D_, b1, H1_, (__hip_bfloat16*)h1, H1P, D_);

    gemm2_ln_kernel<<<M_ / 64, 512, 0, stream>>>(
        h1, W2T, b2, gamma, beta, out);
}